// Round 14
// baseline (215.135 us; speedup 1.0000x reference)
//
#include <hip/hip_runtime.h>
#include <hip/hip_bf16.h>

typedef _Float16 half8 __attribute__((ext_vector_type(8)));
typedef _Float16 half4 __attribute__((ext_vector_type(4)));
typedef _Float16 half2v __attribute__((ext_vector_type(2)));
typedef __fp16 fp16x2 __attribute__((ext_vector_type(2)));
typedef float f32x4 __attribute__((ext_vector_type(4)));
typedef int i32x4 __attribute__((ext_vector_type(4)));

#define BH_ 64
#define L_ 1024
#define DK_ 64

__device__ __forceinline__ unsigned short f2h(float f) {
    _Float16 h = (_Float16)f;
    return __builtin_bit_cast(unsigned short, h);
}
__device__ __forceinline__ unsigned int pk2h(float a, float b) {
    fp16x2 h = __builtin_amdgcn_cvt_pkrtz(a, b);
    return __builtin_bit_cast(unsigned int, h);
}

// ---------------- prep: K -> fp16 AND V -> Vt fp16 transposed (fused) ----
__global__ void prep_kv(const float* __restrict__ K, const float* __restrict__ V,
                        unsigned short* __restrict__ Kh, unsigned short* __restrict__ Vt) {
    __shared__ float lds[64][65];
    if (blockIdx.x < 4096) {
        int idx = blockIdx.x * 256 + threadIdx.x;
        float4 v = reinterpret_cast<const float4*>(K)[idx];
        ushort4 o;
        o.x = f2h(v.x); o.y = f2h(v.y); o.z = f2h(v.z); o.w = f2h(v.w);
        reinterpret_cast<ushort4*>(Kh)[idx] = o;
        return;
    }
    int b = blockIdx.x - 4096;
    int bh = b >> 4, kt = b & 15;
    int t = threadIdx.x;
    const float* Vb = V + ((size_t)bh * L_ + kt * 64) * DK_;
#pragma unroll
    for (int it = 0; it < 4; ++it) {
        int idx = it * 256 + t;
        int row = idx >> 4, c4 = idx & 15;
        float4 v = reinterpret_cast<const float4*>(Vb + (size_t)row * DK_)[c4];
        lds[row][c4 * 4 + 0] = v.x; lds[row][c4 * 4 + 1] = v.y;
        lds[row][c4 * 4 + 2] = v.z; lds[row][c4 * 4 + 3] = v.w;
    }
    __syncthreads();
    unsigned short* Vtb = Vt + (size_t)bh * 64 * L_ + kt * 64;
#pragma unroll
    for (int it = 0; it < 4; ++it) {
        int idx = it * 256 + t;
        int n = idx >> 4, c4 = idx & 15;
        ushort4 o;
        o.x = f2h(lds[c4 * 4 + 0][n]);
        o.y = f2h(lds[c4 * 4 + 1][n]);
        o.z = f2h(lds[c4 * 4 + 2][n]);
        o.w = f2h(lds[c4 * 4 + 3][n]);
        *reinterpret_cast<ushort4*>(Vtb + (size_t)n * L_ + c4 * 4) = o;
    }
}

// ---------------- main fused attention ----------------
// R12 ablation: 4-phase convoy (mask/QK/PV/store additive ~50-60us each),
// and vmcnt FIFO retirement defeats issue-early/wait-late overlap schemes.
// This round removes one convoy stage: masking is DEFERRED to the exp phase
// (softmax shift by max over RAW scores is mathematically equivalent; masked
// p := 0; fully-masked rows have P~2^-1024). Mask is then read per-lane
// (each lane needs exactly its own row/4-col int4) right where it's consumed:
// no LDS nibble pack, no redistribution barrier, one fewer phase.
__global__ __launch_bounds__(256, 4) void attn_main(
    const float* __restrict__ Q, const int* __restrict__ mask,
    const unsigned short* __restrict__ Kh, const unsigned short* __restrict__ Vt,
    float* __restrict__ ctx_out, float* __restrict__ attn_out)
{
    const int qt = blockIdx.x, bh = blockIdx.y;
    const int tid = threadIdx.x;
    const int w = tid >> 6;
    const int lane = tid & 63;
    const int lg = lane >> 4, lr = lane & 15;
    const int q0 = qt * 16;

    __shared__ float red[2][4][16];
    __shared__ union {
        unsigned short p[16][1024];  // swizzled
        float ctxbuf[4][16][68];
    } u;

    auto paddr = [&](int row, int col) -> unsigned short* {
        unsigned byte = (unsigned)row * 2048u +
                        (((unsigned)col * 2u) ^ (((unsigned)(row & 7)) << 4));
        return (unsigned short*)((char*)&u.p[0][0] + byte);
    };

    // Q B-frag: lane holds Q[q0+lr][f*32 + lg*8 + j], fp16
    half8 qh[2];
    {
        const float* qp = Q + ((size_t)bh * L_ + q0 + lr) * DK_ + lg * 8;
#pragma unroll
        for (int f = 0; f < 2; ++f) {
            float4 a = *reinterpret_cast<const float4*>(qp + f * 32);
            float4 b = *reinterpret_cast<const float4*>(qp + f * 32 + 4);
            qh[f][0] = (_Float16)a.x; qh[f][1] = (_Float16)a.y;
            qh[f][2] = (_Float16)a.z; qh[f][3] = (_Float16)a.w;
            qh[f][4] = (_Float16)b.x; qh[f][5] = (_Float16)b.y;
            qh[f][6] = (_Float16)b.z; qh[f][7] = (_Float16)b.w;
        }
    }

    const size_t rowbase = ((size_t)bh * L_ + q0 + lr) * L_;
    const unsigned short* kp = Kh + ((size_t)bh * L_ + w * 256 + lr) * DK_ + lg * 8;
    const int* mp = mask + rowbase + w * 256 + lg * 4;  // lane's own 4 cols

    // ---- QK^T on RAW scores (no mask), K depth-2 prefetch ----
    unsigned int sh[16][2];
    float mx = -INFINITY;

    half8 kc0 = *reinterpret_cast<const half8*>(kp);
    half8 kc1 = *reinterpret_cast<const half8*>(kp + 32);

#pragma unroll
    for (int tt = 0; tt < 16; ++tt) {
        half8 kn0 = kc0, kn1 = kc1;
        if (tt < 15) {
            kn0 = *reinterpret_cast<const half8*>(kp + (tt + 1) * 1024);
            kn1 = *reinterpret_cast<const half8*>(kp + (tt + 1) * 1024 + 32);
        }
        f32x4 acc = {0.f, 0.f, 0.f, 0.f};
        acc = __builtin_amdgcn_mfma_f32_16x16x32_f16(kc0, qh[0], acc, 0, 0, 0);
        acc = __builtin_amdgcn_mfma_f32_16x16x32_f16(kc1, qh[1], acc, 0, 0, 0);
        float s0 = 0.25f * acc[0];
        float s1 = 0.25f * acc[1];
        float s2 = 0.25f * acc[2];
        float s3 = 0.25f * acc[3];
        sh[tt][0] = pk2h(s0, s1);
        sh[tt][1] = pk2h(s2, s3);
        mx = fmaxf(mx, fmaxf(fmaxf(s0, s1), fmaxf(s2, s3)));
        kc0 = kn0; kc1 = kn1;
    }

    // ---- issue first half of mask loads (8 int4 = 32 regs peak) ----
    i32x4 mreg0[8];
#pragma unroll
    for (int tt = 0; tt < 8; ++tt)
        mreg0[tt] = *reinterpret_cast<const i32x4*>(mp + tt * 16);

    // ---- softmax: row max over RAW scores (valid shift; see header) ----
    mx = fmaxf(mx, __shfl_xor(mx, 16));
    mx = fmaxf(mx, __shfl_xor(mx, 32));
    if (lane < 16) red[0][w][lr] = mx;
    __syncthreads();
    const float gm = fmaxf(fmaxf(red[0][0][lr], red[0][1][lr]),
                           fmaxf(red[0][2][lr], red[0][3][lr]));

    // ---- second half of mask loads, then exp with mask applied ----
    i32x4 mreg1[8];
#pragma unroll
    for (int tt = 0; tt < 8; ++tt)
        mreg1[tt] = *reinterpret_cast<const i32x4*>(mp + (tt + 8) * 16);

    float lsum = 0.f;
#pragma unroll
    for (int tt = 0; tt < 16; ++tt) {
        half2v a = __builtin_bit_cast(half2v, sh[tt][0]);
        half2v b = __builtin_bit_cast(half2v, sh[tt][1]);
        i32x4 m = (tt < 8) ? mreg0[tt] : mreg1[tt - 8];
        float p0 = m[0] ? 0.f : __expf((float)a[0] - gm);
        float p1 = m[1] ? 0.f : __expf((float)a[1] - gm);
        float p2 = m[2] ? 0.f : __expf((float)b[0] - gm);
        float p3 = m[3] ? 0.f : __expf((float)b[1] - gm);
        lsum += (p0 + p1) + (p2 + p3);
        sh[tt][0] = pk2h(p0, p1);
        sh[tt][1] = pk2h(p2, p3);
    }
    lsum += __shfl_xor(lsum, 16);
    lsum += __shfl_xor(lsum, 32);
    if (lane < 16) red[1][w][lr] = lsum;

    // ---- p -> swizzled LDS (wave-private strip) ----
#pragma unroll
    for (int tt = 0; tt < 16; ++tt) {
        uint2 pr; pr.x = sh[tt][0]; pr.y = sh[tt][1];
        *reinterpret_cast<uint2*>(paddr(lr, w * 256 + tt * 16 + lg * 4)) = pr;
    }

    // ---- PV: read p from LDS (wave-private), V depth-1 prefetch ----
    const unsigned short* vp = Vt + ((size_t)bh * 64 + lr) * L_ + w * 256 + lg * 8;
    f32x4 cacc[4] = {{0,0,0,0},{0,0,0,0},{0,0,0,0},{0,0,0,0}};
    half8 vb0 = *reinterpret_cast<const half8*>(vp);
    half8 vb1 = *reinterpret_cast<const half8*>(vp + 16384);
    half8 vb2 = *reinterpret_cast<const half8*>(vp + 32768);
    half8 vb3 = *reinterpret_cast<const half8*>(vp + 49152);

#pragma unroll
    for (int c = 0; c < 8; ++c) {
        half8 vn0 = vb0, vn1 = vb1, vn2 = vb2, vn3 = vb3;
        if (c < 7) {
            vn0 = *reinterpret_cast<const half8*>(vp + (c + 1) * 32);
            vn1 = *reinterpret_cast<const half8*>(vp + 16384 + (c + 1) * 32);
            vn2 = *reinterpret_cast<const half8*>(vp + 32768 + (c + 1) * 32);
            vn3 = *reinterpret_cast<const half8*>(vp + 49152 + (c + 1) * 32);
        }
        half8 pa = *reinterpret_cast<const half8*>(paddr(lr, w * 256 + c * 32 + lg * 8));
        cacc[0] = __builtin_amdgcn_mfma_f32_16x16x32_f16(pa, vb0, cacc[0], 0, 0, 0);
        cacc[1] = __builtin_amdgcn_mfma_f32_16x16x32_f16(pa, vb1, cacc[1], 0, 0, 0);
        cacc[2] = __builtin_amdgcn_mfma_f32_16x16x32_f16(pa, vb2, cacc[2], 0, 0, 0);
        cacc[3] = __builtin_amdgcn_mfma_f32_16x16x32_f16(pa, vb3, cacc[3], 0, 0, 0);
        vb0 = vn0; vb1 = vn1; vb2 = vn2; vb3 = vn3;
    }

    __syncthreads();   // all p strips + red[1] visible

    // ---- pull attn-store data into registers (p dies after this) ----
    half4 preg[4][4];
    float rqv[4];
#pragma unroll
    for (int rr = 0; rr < 4; ++rr) {
        const int q = w * 4 + rr;
        rqv[rr] = 1.0f / (red[1][0][q] + red[1][1][q] +
                          red[1][2][q] + red[1][3][q]);
#pragma unroll
        for (int i = 0; i < 4; ++i)
            preg[rr][i] = *reinterpret_cast<const half4*>(paddr(q, i * 256 + lane * 4));
    }

    __syncthreads();   // p reads done -> ctxbuf may overwrite

    // ---- combine partial contexts across waves, ctx store ----
#pragma unroll
    for (int nt = 0; nt < 4; ++nt)
#pragma unroll
        for (int r = 0; r < 4; ++r)
            u.ctxbuf[w][lg * 4 + r][nt * 16 + lr] = cacc[nt][r];
    __syncthreads();
    {
        int e = tid * 4;
        int q = e >> 6, n = e & 63;
        float gs = red[1][0][q] + red[1][1][q] + red[1][2][q] + red[1][3][q];
        float rq = 1.0f / gs;
        float4 a0 = *reinterpret_cast<float4*>(&u.ctxbuf[0][q][n]);
        float4 a1 = *reinterpret_cast<float4*>(&u.ctxbuf[1][q][n]);
        float4 a2 = *reinterpret_cast<float4*>(&u.ctxbuf[2][q][n]);
        float4 a3 = *reinterpret_cast<float4*>(&u.ctxbuf[3][q][n]);
        float4 o;
        o.x = (a0.x + a1.x + a2.x + a3.x) * rq;
        o.y = (a0.y + a1.y + a2.y + a3.y) * rq;
        o.z = (a0.z + a1.z + a2.z + a3.z) * rq;
        o.w = (a0.w + a1.w + a2.w + a3.w) * rq;
        *reinterpret_cast<float4*>(&ctx_out[((size_t)bh * L_ + q0 + q) * DK_ + n]) = o;
    }

    // ---- attn stores LAST, fire-and-forget (wave-sequential row bursts) ----
#pragma unroll
    for (int rr = 0; rr < 4; ++rr) {
        const int q = w * 4 + rr;
        const float rq = rqv[rr];
        float* orow = attn_out + ((size_t)bh * L_ + q0 + q) * L_;
#pragma unroll
        for (int i = 0; i < 4; ++i) {
            half4 v = preg[rr][i];
            float4 o;
            o.x = (float)v[0] * rq; o.y = (float)v[1] * rq;
            o.z = (float)v[2] * rq; o.w = (float)v[3] * rq;
            *reinterpret_cast<float4*>(orow + i * 256 + lane * 4) = o;
        }
    }
}

extern "C" void kernel_launch(void* const* d_in, const int* in_sizes, int n_in,
                              void* d_out, int out_size, void* d_ws, size_t ws_size,
                              hipStream_t stream) {
    const float* Q = (const float*)d_in[0];
    const float* K = (const float*)d_in[1];
    const float* V = (const float*)d_in[2];
    const int* mask = (const int*)d_in[3];
    float* ctx_out = (float*)d_out;
    float* attn_out = ctx_out + (size_t)BH_ * L_ * DK_;

    unsigned short* Kh = (unsigned short*)d_ws;
    unsigned short* Vt = Kh + (size_t)BH_ * L_ * DK_;

    hipLaunchKernelGGL(prep_kv, dim3(5120), dim3(256), 0, stream, K, V, Kh, Vt);
    hipLaunchKernelGGL(attn_main, dim3(64, 64), dim3(256), 0, stream,
                       Q, mask, Kh, Vt, ctx_out, attn_out);
}